// Round 4
// baseline (271.160 us; speedup 1.0000x reference)
//
#include <hip/hip_runtime.h>
#include <hip/hip_bf16.h>
#include <stdint.h>

typedef unsigned short u16;
typedef unsigned int   u32;

#define N_DIM  1024
#define IN_DIM 1024
#define H_DIM  64
#define BATCH  16

typedef __bf16 bf16x8 __attribute__((ext_vector_type(8)));
typedef float  f32x4  __attribute__((ext_vector_type(4)));

// round-to-nearest-even fp32 -> bf16 (bit pattern)
__device__ inline u16 f2bf(float f) {
    union { float f; u32 u; } v; v.f = f;
    u32 u = v.u;
    return (u16)((u + 0x7fffu + ((u >> 16) & 1u)) >> 16);
}
// packed pair: v_cvt_pk_bf16_f32 when available
__device__ inline u32 pack2(float a, float b) {
    __hip_bfloat162 h = __float22bfloat162_rn(float2{a, b});
    union { __hip_bfloat162 h; u32 u; } cv; cv.h = h; return cv.u;
}

// ---------------------------------------------------------------------------
// prep (merged): blocks 0..255 = G transpose tiles + per-jtile rowsum partials
//                blocks 256..767 = Q/Kw transpose-cast
__global__ __launch_bounds__(256) void prep(
        const float* __restrict__ G, const float* __restrict__ Q,
        const float* __restrict__ Kw, u16* __restrict__ Gbt,
        float* __restrict__ Grp, u16* __restrict__ QT, u16* __restrict__ KwT) {
    int bid = blockIdx.x;
    if (bid >= 256) {
        int idx = (bid - 256) * 256 + threadIdx.x;      // 0 .. 131071
        const float* src = (idx < 65536) ? Q : Kw;
        u16* dst = (idx < 65536) ? QT : KwT;
        int i = idx & 65535;
        int h = i >> 10;         // 0..63
        int n = i & 1023;        // 0..1023 (contiguous store)
        dst[h * 1024 + n] = f2bf(src[n * 64 + h]);
        return;
    }
    __shared__ float tile[64][65];
    int jt = bid & 15, it = bid >> 4;
    int i0 = it * 64, j0 = jt * 64;
    int tx = threadIdx.x & 63, ty = threadIdx.x >> 6;   // ty 0..3
    for (int r = 0; r < 16; ++r) {
        int i = ty * 16 + r;
        tile[i][tx] = G[(size_t)(i0 + i) * 1024 + j0 + tx];
    }
    __syncthreads();
    for (int r = 0; r < 16; ++r) {
        int j = ty * 16 + r;
        Gbt[(size_t)(j0 + j) * 1024 + i0 + tx] = f2bf(tile[tx][j]);
    }
    if (ty == 0) {
        float sum = 0.f;
        for (int j = 0; j < 64; ++j) sum += tile[tx][j];
        Grp[jt * 1024 + i0 + tx] = sum;                 // plain store, no atomics
    }
}

// ---------------------------------------------------------------------------
// qkt (merged): z==0 -> q[b][n][h] = sum_i s[n][b][i] Qw[i][h]
//               z==1 -> kt[b][i][h] = sum_n s[n][b][i] Kw[n][h]
__global__ __launch_bounds__(512, 4) void qkt(
        const float* __restrict__ s, const u16* __restrict__ QT,
        const u16* __restrict__ KwT, const float* __restrict__ Grp,
        u16* __restrict__ qws, u16* __restrict__ ktws, float* __restrict__ Grsum) {
    int b = blockIdx.y;
    int t = threadIdx.x, lane = t & 63, w = t >> 6, quad = lane >> 4, l15 = lane & 15;
    __shared__ __align__(16) u16 sh[2][2][64][34];     // kt staging; q aliases as 16KB reduce
    float* red = (float*)sh;

    if (blockIdx.z == 0) {
        // ---------------- q role ----------------
        if (blockIdx.y == 0 && t < 64) {               // Grsum finalize (16 x-blocks cover 1024 i)
            int i = blockIdx.x * 64 + t;
            float g = 0.f;
            for (int jt = 0; jt < 16; ++jt) g += Grp[jt * 1024 + i];
            Grsum[i] = g;
        }
        int n0 = blockIdx.x * 64;
        int wm = (w & 3) * 16;                         // m-quarter within 64
        int kb = (w >> 2) * 512;                       // k-half
        const float* arow = s + (size_t)(n0 + wm + l15) * (BATCH * IN_DIM)
                              + (size_t)b * IN_DIM + kb + quad * 8;
        const u16* bbase = QT + (size_t)l15 * 1024 + kb + quad * 8;

        f32x4 acc[4] = {};
        float4 A0[3], A1[3];
        bf16x8 Bf[2][4];
        A0[0] = ((const float4*)arow)[0];
        A1[0] = ((const float4*)arow)[1];
        A0[1] = ((const float4*)(arow + 32))[0];
        A1[1] = ((const float4*)(arow + 32))[1];
#pragma unroll
        for (int ct = 0; ct < 4; ++ct)
            Bf[0][ct] = *(const bf16x8*)&bbase[ct * 16384];

#pragma unroll
        for (int st = 0; st < 16; ++st) {              // 16 steps of k=32
            int cur = st % 3, cb = st & 1;
            if (st < 14) {                             // A prefetch depth 3 (HBM)
                const float4* ap = (const float4*)(arow + (size_t)(st + 2) * 32);
                A0[(st + 2) % 3] = ap[0];
                A1[(st + 2) % 3] = ap[1];
            }
            if (st < 15) {                             // B prefetch depth 2 (L2)
#pragma unroll
                for (int ct = 0; ct < 4; ++ct)
                    Bf[cb ^ 1][ct] = *(const bf16x8*)&bbase[ct * 16384 + (st + 1) * 32];
            }
            float4 fa = A0[cur], fb = A1[cur];
            union { uint4 u; bf16x8 v; } cu;
            cu.u = (uint4){ pack2(fa.x, fa.y), pack2(fa.z, fa.w),
                            pack2(fb.x, fb.y), pack2(fb.z, fb.w) };
#pragma unroll
            for (int ct = 0; ct < 4; ++ct)
                acc[ct] = __builtin_amdgcn_mfma_f32_16x16x32_bf16(cu.v, Bf[cb][ct], acc[ct], 0, 0, 0);
        }

        // cross-k-half reduce through LDS
        if (w >= 4) {
            float* dst = red + ((w - 4) * 64 + lane) * 16;
#pragma unroll
            for (int ct = 0; ct < 4; ++ct) *(f32x4*)&dst[ct * 4] = acc[ct];
        }
        __syncthreads();
        if (w < 4) {
            const float* sp2 = red + (w * 64 + lane) * 16;
            u16* ob = qws + (size_t)b * 65536;
#pragma unroll
            for (int ct = 0; ct < 4; ++ct) {
                f32x4 o = *(const f32x4*)&sp2[ct * 4];
#pragma unroll
                for (int r = 0; r < 4; ++r) {
                    int m = n0 + wm + quad * 4 + r;
                    ob[(size_t)m * 64 + ct * 16 + l15] = f2bf(acc[ct][r] + o[r]);
                }
            }
        }
        return;
    }

    // ---------------- kt role ----------------
    int i0 = blockIdx.x * 64;
    int half = w >> 2;                                 // compute n-half
    int wm = (w & 3) * 16;                             // i-quarter
    int shalf = t >> 8, nr = (t & 255) >> 3, iofs = (t & 7) * 8;  // staging role
    const float* sp = s + (size_t)(shalf * 512 + nr) * (BATCH * IN_DIM)
                        + (size_t)b * IN_DIM + i0 + iofs;
    const u16* bbase = KwT + (size_t)l15 * 1024 + half * 512 + quad * 8;

    f32x4 acc[4] = {};
    float4 P0[2], P1[2];
    bf16x8 Bf[2][4];
    P0[0] = ((const float4*)sp)[0];
    P1[0] = ((const float4*)sp)[1];
    {
        const float4* p = (const float4*)(sp + (size_t)32 * 16384);
        P0[1] = p[0]; P1[1] = p[1];
    }
#pragma unroll
    for (int ct = 0; ct < 4; ++ct)
        Bf[0][ct] = *(const bf16x8*)&bbase[ct * 16384];

#pragma unroll
    for (int c = 0; c < 16; ++c) {                     // 16 chunks of n=32 per half
        int buf = c & 1;
        float4 fa = P0[buf], fb = P1[buf];
        u16* wp = &sh[shalf][buf][iofs][nr];
        wp[0]   = f2bf(fa.x);
        wp[34]  = f2bf(fa.y);
        wp[68]  = f2bf(fa.z);
        wp[102] = f2bf(fa.w);
        wp[136] = f2bf(fb.x);
        wp[170] = f2bf(fb.y);
        wp[204] = f2bf(fb.z);
        wp[238] = f2bf(fb.w);
        __syncthreads();                               // buf ready (both halves)
        if (c < 14) {                                  // prefetch chunk c+2 (HBM/L3)
            const float4* p = (const float4*)(sp + (size_t)(c + 2) * 32 * 16384);
            P0[buf] = p[0]; P1[buf] = p[1];
        }
        if (c < 15) {                                  // prefetch next B-frags (L2)
#pragma unroll
            for (int ct = 0; ct < 4; ++ct)
                Bf[(c + 1) & 1][ct] = *(const bf16x8*)&bbase[ct * 16384 + (c + 1) * 32];
        }
        const u32* ap = (const u32*)&sh[half][buf][wm + l15][quad * 8];
        union { u32 u[4]; bf16x8 v; } au;
        au.u[0] = ap[0]; au.u[1] = ap[1]; au.u[2] = ap[2]; au.u[3] = ap[3];
#pragma unroll
        for (int ct = 0; ct < 4; ++ct)
            acc[ct] = __builtin_amdgcn_mfma_f32_16x16x32_bf16(au.v, Bf[buf][ct], acc[ct], 0, 0, 0);
    }

    __syncthreads();                                   // staging reads all done
    if (w >= 4) {
        float* dst = red + ((w - 4) * 64 + lane) * 16;
#pragma unroll
        for (int ct = 0; ct < 4; ++ct) *(f32x4*)&dst[ct * 4] = acc[ct];
    }
    __syncthreads();
    if (w < 4) {
        const float* sp2 = red + (w * 64 + lane) * 16;
        u16* ob = ktws + (size_t)b * 65536;
#pragma unroll
        for (int ct = 0; ct < 4; ++ct) {
            f32x4 o = *(const f32x4*)&sp2[ct * 4];
#pragma unroll
            for (int r = 0; r < 4; ++r) {
                int i = i0 + wm + quad * 4 + r;
                ob[(size_t)i * 64 + ct * 16 + l15] = f2bf(acc[ct][r] + o[r]);
            }
        }
    }
}

// ---------------------------------------------------------------------------
// gemm_fused v4: no LDS staging for Gbt at all.
// Block = 64m x 256n per b; grid (4 n-tiles, 16 m-tiles, 16 b) = 1024 blocks;
// 512 threads = 8 waves, 2 blocks/CU (launch_bounds VGPR cap 128).
// Per K-step (32 i):
//   - issue Gbt B-frags (wave's 32n slice) DIRECT from global (L2-resident,
//     same bytes the old gl_lds staging pulled, minus all LDS machinery)
//   - score: wave's 16m x 16i tile = mfma(kt_frag, q_frag) x2 (kt direct from
//     L2, 1-iter register prefetch)
//   - epilogue: square(+1e-9), Grsum-weighted rowsum partial (Grsum read
//     direct from global, L1-broadcast), pack bf16 -> As[buf] (dbuf, 10KB)
//   - ONE __syncthreads, then agg: acc[4mf][2nf] += As(64m x 32i) @ gb
// LDS per wave-iter: 4 b128 reads + 1 b64 write (was ~14 reads + staging).
__global__ __launch_bounds__(512, 4) void gemm_fused(
        const u16* __restrict__ qws, const u16* __restrict__ ktws,
        const u16* __restrict__ Gbt, const float* __restrict__ Grsum,
        float* __restrict__ out) {
    int b = blockIdx.z;
    int n0 = blockIdx.x * 256, m0 = blockIdx.y * 64;
    const u16* qb = qws  + (size_t)b * 65536;
    const u16* kb = ktws + (size_t)b * 65536;
    __shared__ __align__(16) u16 As[2][64 * 40];     // score->agg, dbuf, padded pitch
    __shared__ float rs[64];
    int t = threadIdx.x, lane = t & 63, w = t >> 6, quad = lane >> 4, l15 = lane & 15;
    int ti = w & 1;            // score i-subtile (16 of 32)
    int sm = (w >> 1) * 16;    // score m-16-row block (4 blocks x 2 ti = 8 waves)
    int wn = w * 32;           // agg n-slice (8 x 32 = 256)

    if (t < 64) rs[t] = 0.f;

    // K-invariant q B-frags: q[m][h], lane holds col=m=l15, k=h
    bf16x8 qf[2];
#pragma unroll
    for (int kick = 0; kick < 2; ++kick)
        qf[kick] = *(const bf16x8*)&qb[(size_t)(m0 + sm + l15) * 64 + kick*32 + quad*8];

    // kt A-frags for iter 0: kt[i][h], lane holds row=i=l15, k=h
    bf16x8 kc[2], kn[2];
#pragma unroll
    for (int kick = 0; kick < 2; ++kick)
        kc[kick] = *(const bf16x8*)&kb[(size_t)(ti*16 + l15) * 64 + kick*32 + quad*8];

    f32x4 acc[4][2] = {};
    float partial = 0.f;

    for (int kk = 0; kk < 32; ++kk) {
        int buf = kk & 1;
        // ---- issue this iter's Gbt B-frags early (global/L2); consumed post-barrier
        bf16x8 gb[2];
#pragma unroll
        for (int nf = 0; nf < 2; ++nf)
            gb[nf] = *(const bf16x8*)&Gbt[(size_t)(n0 + wn + nf*16 + l15) * 1024 + kk*32 + quad*8];
        // ---- prefetch next iter's kt frags
        if (kk < 31) {
#pragma unroll
            for (int kick = 0; kick < 2; ++kick)
                kn[kick] = *(const bf16x8*)&kb[(size_t)((kk+1)*32 + ti*16 + l15) * 64 + kick*32 + quad*8];
        }
        // ---- score: 16m x 16i tile; D[row=i-local][col=m-local]
        f32x4 sacc = {};
#pragma unroll
        for (int kick = 0; kick < 2; ++kick)
            sacc = __builtin_amdgcn_mfma_f32_16x16x32_bf16(kc[kick], qf[kick], sacc, 0, 0, 0);
        // ---- epilogue: square, weighted rowsum partial, pack to As[buf]
        float4 g = *(const float4*)&Grsum[kk * 32 + ti * 16 + quad * 4];
        float v0 = sacc[0] * 0.125f + 1e-9f; v0 *= v0;
        float v1 = sacc[1] * 0.125f + 1e-9f; v1 *= v1;
        float v2 = sacc[2] * 0.125f + 1e-9f; v2 *= v2;
        float v3 = sacc[3] * 0.125f + 1e-9f; v3 *= v3;
        partial += v0 * g.x + v1 * g.y + v2 * g.z + v3 * g.w;
        uint2 pk = { pack2(v0, v1), pack2(v2, v3) };
        *(uint2*)&As[buf][(sm + l15) * 40 + ti*16 + quad*4] = pk;
        __syncthreads();                           // As[buf] ready (all 8 waves)
        // ---- agg: acc[4mf][2nf] += As(64m x 32k) @ gb(32n x 32k)
#pragma unroll
        for (int mf = 0; mf < 4; ++mf) {
            bf16x8 af = *(const bf16x8*)&As[buf][(mf*16 + l15) * 40 + quad*8];
            acc[mf][0] = __builtin_amdgcn_mfma_f32_16x16x32_bf16(af, gb[0], acc[mf][0], 0, 0, 0);
            acc[mf][1] = __builtin_amdgcn_mfma_f32_16x16x32_bf16(af, gb[1], acc[mf][1], 0, 0, 0);
        }
        // rotate kt register buffers
        kc[0] = kn[0]; kc[1] = kn[1];
    }

    // rowsum: lane holds partial for m = sm+l15 over its (ti,quad) i-subset;
    // reduce across quads in-wave, then across ti-waves via LDS atomics.
    partial += __shfl_xor(partial, 16, 64);
    partial += __shfl_xor(partial, 32, 64);
    if (quad == 0) atomicAdd(&rs[sm + l15], partial);
    __syncthreads();
    if (t < 64) rs[t] = 1.0f / (rs[t] + 0.001f);
    __syncthreads();

#pragma unroll
    for (int mf = 0; mf < 4; ++mf) {
        float4 rv = *(const float4*)&rs[mf * 16 + quad * 4];
        float rva[4] = { rv.x, rv.y, rv.z, rv.w };
#pragma unroll
        for (int r = 0; r < 4; ++r) {
            int m = m0 + mf * 16 + quad * 4 + r;
            float* orow = out + (size_t)m * (BATCH * IN_DIM) + (size_t)b * IN_DIM + n0 + wn;
#pragma unroll
            for (int nf = 0; nf < 2; ++nf)
                orow[nf * 16 + l15] = acc[mf][nf][r] * rva[r];
        }
    }
}

// ---------------------------------------------------------------------------
extern "C" void kernel_launch(void* const* d_in, const int* in_sizes, int n_in,
                              void* d_out, int out_size, void* d_ws, size_t ws_size,
                              hipStream_t stream) {
    const float* s  = (const float*)d_in[0];
    const float* G  = (const float*)d_in[1];
    const float* Q  = (const float*)d_in[2];
    const float* Kw = (const float*)d_in[3];
    float* out = (float*)d_out;
    char* ws = (char*)d_ws;

    u16*   qws   = (u16*)(ws);                                    // 2 MB
    u16*   ktws  = (u16*)(ws + (size_t)(2u << 20));               // 2 MB
    u16*   Gbt   = (u16*)(ws + (size_t)(4u << 20));               // 2 MB
    u16*   QT    = (u16*)(ws + (size_t)(6u << 20));               // 128 KB
    u16*   KwT   = (u16*)(ws + (size_t)(6u << 20) + (128u << 10)); // 128 KB
    float* Grsum = (float*)(ws + (size_t)(6u << 20) + (256u << 10)); // 4 KB
    float* Grp   = (float*)(ws + (size_t)(6u << 20) + (260u << 10)); // 64 KB

    prep<<<768, 256, 0, stream>>>(G, Q, Kw, Gbt, Grp, QT, KwT);
    qkt<<<dim3(16, 16, 2), 512, 0, stream>>>(s, QT, KwT, Grp, qws, ktws, Grsum);
    gemm_fused<<<dim3(4, 16, 16), 512, 0, stream>>>(qws, ktws, Gbt, Grsum, out);
}

// Round 5
// 192.681 us; speedup vs baseline: 1.4073x; 1.4073x over previous
//
#include <hip/hip_runtime.h>
#include <hip/hip_bf16.h>
#include <stdint.h>

typedef unsigned short u16;
typedef unsigned int   u32;

#define N_DIM  1024
#define IN_DIM 1024
#define H_DIM  64
#define BATCH  16

typedef __bf16 bf16x8 __attribute__((ext_vector_type(8)));
typedef float  f32x4  __attribute__((ext_vector_type(4)));

// round-to-nearest-even fp32 -> bf16 (bit pattern)
__device__ inline u16 f2bf(float f) {
    union { float f; u32 u; } v; v.f = f;
    u32 u = v.u;
    return (u16)((u + 0x7fffu + ((u >> 16) & 1u)) >> 16);
}
// packed pair: v_cvt_pk_bf16_f32 when available
__device__ inline u32 pack2(float a, float b) {
    __hip_bfloat162 h = __float22bfloat162_rn(float2{a, b});
    union { __hip_bfloat162 h; u32 u; } cv; cv.h = h; return cv.u;
}

// async global->LDS, 16B per lane. LDS dest must be wave-uniform base + lane*16.
__device__ inline void gl_lds16(const u16* g, u16* l) {
    __builtin_amdgcn_global_load_lds(
        (const __attribute__((address_space(1))) u32*)g,
        (__attribute__((address_space(3))) u32*)l, 16, 0, 0);
}

// ---------------------------------------------------------------------------
// prep (merged): blocks 0..255 = G transpose tiles + per-jtile rowsum partials
//                blocks 256..767 = Q/Kw transpose-cast
__global__ __launch_bounds__(256) void prep(
        const float* __restrict__ G, const float* __restrict__ Q,
        const float* __restrict__ Kw, u16* __restrict__ Gbt,
        float* __restrict__ Grp, u16* __restrict__ QT, u16* __restrict__ KwT) {
    int bid = blockIdx.x;
    if (bid >= 256) {
        int idx = (bid - 256) * 256 + threadIdx.x;      // 0 .. 131071
        const float* src = (idx < 65536) ? Q : Kw;
        u16* dst = (idx < 65536) ? QT : KwT;
        int i = idx & 65535;
        int h = i >> 10;         // 0..63
        int n = i & 1023;        // 0..1023 (contiguous store)
        dst[h * 1024 + n] = f2bf(src[n * 64 + h]);
        return;
    }
    __shared__ float tile[64][65];
    int jt = bid & 15, it = bid >> 4;
    int i0 = it * 64, j0 = jt * 64;
    int tx = threadIdx.x & 63, ty = threadIdx.x >> 6;   // ty 0..3
    for (int r = 0; r < 16; ++r) {
        int i = ty * 16 + r;
        tile[i][tx] = G[(size_t)(i0 + i) * 1024 + j0 + tx];
    }
    __syncthreads();
    for (int r = 0; r < 16; ++r) {
        int j = ty * 16 + r;
        Gbt[(size_t)(j0 + j) * 1024 + i0 + tx] = f2bf(tile[tx][j]);
    }
    if (ty == 0) {
        float sum = 0.f;
        for (int j = 0; j < 64; ++j) sum += tile[tx][j];
        Grp[jt * 1024 + i0 + tx] = sum;                 // plain store, no atomics
    }
}

// ---------------------------------------------------------------------------
// qkt (merged): z==0 -> q[b][n][h] = sum_i s[n][b][i] Qw[i][h]
//               z==1 -> kt[b][i][h] = sum_n s[n][b][i] Kw[n][h]
__global__ __launch_bounds__(512, 4) void qkt(
        const float* __restrict__ s, const u16* __restrict__ QT,
        const u16* __restrict__ KwT, const float* __restrict__ Grp,
        u16* __restrict__ qws, u16* __restrict__ ktws, float* __restrict__ Grsum) {
    int b = blockIdx.y;
    int t = threadIdx.x, lane = t & 63, w = t >> 6, quad = lane >> 4, l15 = lane & 15;
    __shared__ __align__(16) u16 sh[2][2][64][34];     // kt staging; q aliases as 16KB reduce
    float* red = (float*)sh;

    if (blockIdx.z == 0) {
        // ---------------- q role ----------------
        if (blockIdx.y == 0 && t < 64) {               // Grsum finalize (16 x-blocks cover 1024 i)
            int i = blockIdx.x * 64 + t;
            float g = 0.f;
            for (int jt = 0; jt < 16; ++jt) g += Grp[jt * 1024 + i];
            Grsum[i] = g;
        }
        int n0 = blockIdx.x * 64;
        int wm = (w & 3) * 16;                         // m-quarter within 64
        int kb = (w >> 2) * 512;                       // k-half
        const float* arow = s + (size_t)(n0 + wm + l15) * (BATCH * IN_DIM)
                              + (size_t)b * IN_DIM + kb + quad * 8;
        const u16* bbase = QT + (size_t)l15 * 1024 + kb + quad * 8;

        f32x4 acc[4] = {};
        float4 A0[3], A1[3];
        bf16x8 Bf[2][4];
        A0[0] = ((const float4*)arow)[0];
        A1[0] = ((const float4*)arow)[1];
        A0[1] = ((const float4*)(arow + 32))[0];
        A1[1] = ((const float4*)(arow + 32))[1];
#pragma unroll
        for (int ct = 0; ct < 4; ++ct)
            Bf[0][ct] = *(const bf16x8*)&bbase[ct * 16384];

#pragma unroll
        for (int st = 0; st < 16; ++st) {              // 16 steps of k=32
            int cur = st % 3, cb = st & 1;
            if (st < 14) {                             // A prefetch depth 3 (HBM)
                const float4* ap = (const float4*)(arow + (size_t)(st + 2) * 32);
                A0[(st + 2) % 3] = ap[0];
                A1[(st + 2) % 3] = ap[1];
            }
            if (st < 15) {                             // B prefetch depth 2 (L2)
#pragma unroll
                for (int ct = 0; ct < 4; ++ct)
                    Bf[cb ^ 1][ct] = *(const bf16x8*)&bbase[ct * 16384 + (st + 1) * 32];
            }
            float4 fa = A0[cur], fb = A1[cur];
            union { uint4 u; bf16x8 v; } cu;
            cu.u = (uint4){ pack2(fa.x, fa.y), pack2(fa.z, fa.w),
                            pack2(fb.x, fb.y), pack2(fb.z, fb.w) };
#pragma unroll
            for (int ct = 0; ct < 4; ++ct)
                acc[ct] = __builtin_amdgcn_mfma_f32_16x16x32_bf16(cu.v, Bf[cb][ct], acc[ct], 0, 0, 0);
        }

        // cross-k-half reduce through LDS
        if (w >= 4) {
            float* dst = red + ((w - 4) * 64 + lane) * 16;
#pragma unroll
            for (int ct = 0; ct < 4; ++ct) *(f32x4*)&dst[ct * 4] = acc[ct];
        }
        __syncthreads();
        if (w < 4) {
            const float* sp2 = red + (w * 64 + lane) * 16;
            u16* ob = qws + (size_t)b * 65536;
#pragma unroll
            for (int ct = 0; ct < 4; ++ct) {
                f32x4 o = *(const f32x4*)&sp2[ct * 4];
#pragma unroll
                for (int r = 0; r < 4; ++r) {
                    int m = n0 + wm + quad * 4 + r;
                    ob[(size_t)m * 64 + ct * 16 + l15] = f2bf(acc[ct][r] + o[r]);
                }
            }
        }
        return;
    }

    // ---------------- kt role ----------------
    int i0 = blockIdx.x * 64;
    int half = w >> 2;                                 // compute n-half
    int wm = (w & 3) * 16;                             // i-quarter
    int shalf = t >> 8, nr = (t & 255) >> 3, iofs = (t & 7) * 8;  // staging role
    const float* sp = s + (size_t)(shalf * 512 + nr) * (BATCH * IN_DIM)
                        + (size_t)b * IN_DIM + i0 + iofs;
    const u16* bbase = KwT + (size_t)l15 * 1024 + half * 512 + quad * 8;

    f32x4 acc[4] = {};
    float4 P0[2], P1[2];
    bf16x8 Bf[2][4];
    P0[0] = ((const float4*)sp)[0];
    P1[0] = ((const float4*)sp)[1];
    {
        const float4* p = (const float4*)(sp + (size_t)32 * 16384);
        P0[1] = p[0]; P1[1] = p[1];
    }
#pragma unroll
    for (int ct = 0; ct < 4; ++ct)
        Bf[0][ct] = *(const bf16x8*)&bbase[ct * 16384];

#pragma unroll
    for (int c = 0; c < 16; ++c) {                     // 16 chunks of n=32 per half
        int buf = c & 1;
        float4 fa = P0[buf], fb = P1[buf];
        u16* wp = &sh[shalf][buf][iofs][nr];
        wp[0]   = f2bf(fa.x);
        wp[34]  = f2bf(fa.y);
        wp[68]  = f2bf(fa.z);
        wp[102] = f2bf(fa.w);
        wp[136] = f2bf(fb.x);
        wp[170] = f2bf(fb.y);
        wp[204] = f2bf(fb.z);
        wp[238] = f2bf(fb.w);
        __syncthreads();                               // buf ready (both halves)
        if (c < 14) {                                  // prefetch chunk c+2 (HBM/L3)
            const float4* p = (const float4*)(sp + (size_t)(c + 2) * 32 * 16384);
            P0[buf] = p[0]; P1[buf] = p[1];
        }
        if (c < 15) {                                  // prefetch next B-frags (L2)
#pragma unroll
            for (int ct = 0; ct < 4; ++ct)
                Bf[(c + 1) & 1][ct] = *(const bf16x8*)&bbase[ct * 16384 + (c + 1) * 32];
        }
        const u32* ap = (const u32*)&sh[half][buf][wm + l15][quad * 8];
        union { u32 u[4]; bf16x8 v; } au;
        au.u[0] = ap[0]; au.u[1] = ap[1]; au.u[2] = ap[2]; au.u[3] = ap[3];
#pragma unroll
        for (int ct = 0; ct < 4; ++ct)
            acc[ct] = __builtin_amdgcn_mfma_f32_16x16x32_bf16(au.v, Bf[buf][ct], acc[ct], 0, 0, 0);
    }

    __syncthreads();                                   // staging reads all done
    if (w >= 4) {
        float* dst = red + ((w - 4) * 64 + lane) * 16;
#pragma unroll
        for (int ct = 0; ct < 4; ++ct) *(f32x4*)&dst[ct * 4] = acc[ct];
    }
    __syncthreads();
    if (w < 4) {
        const float* sp2 = red + (w * 64 + lane) * 16;
        u16* ob = ktws + (size_t)b * 65536;
#pragma unroll
        for (int ct = 0; ct < 4; ++ct) {
            f32x4 o = *(const f32x4*)&sp2[ct * 4];
#pragma unroll
            for (int r = 0; r < 4; ++r) {
                int i = i0 + wm + quad * 4 + r;
                ob[(size_t)i * 64 + ct * 16 + l15] = f2bf(acc[ct][r] + o[r]);
            }
        }
    }
}

// ---------------------------------------------------------------------------
// gemm_fused v5: r2 geometry (128m x 256n, 4 waves, 2 blocks/CU) with a
// 1-iteration software pipeline so only ONE barrier per K-step is needed:
//   iter kk: [barrier] -> issue gl_lds chunk kk+1 -> Bs[(kk+1)%3] (full iter
//   in flight before any drain) -> load kreg chunk kk+1 -> score kk from
//   ktc[kk&1] -> epilogue+pack -> As[kk&1] -> agg of step kk-1 from
//   As[(kk-1)&1] @ Bs[(kk-1)%3] -> write ktc[(kk+1)&1].
// Every RAW/WAR hazard crosses exactly one barrier (As/ktc dbuf, Bs 3-buf).
// ktc pitch 72 -> 68 u16: write bank pattern (36ir+4ch)%32 (8-way) becomes
// (2ir+4ch)%32 (~2-way, free per m136).
__global__ __launch_bounds__(256, 2) void gemm_fused(
        const u16* __restrict__ qws, const u16* __restrict__ ktws,
        const u16* __restrict__ Gbt, const float* __restrict__ Grsum,
        float* __restrict__ out) {
    int b = blockIdx.z;
    int n0 = blockIdx.x * 256, m0 = blockIdx.y * 128;
    const u16* qb = qws  + (size_t)b * 65536;
    const u16* kb = ktws + (size_t)b * 65536;
    __shared__ __align__(16) u16 As[2][128 * 40];    // score->agg, dbuf (pipeline)
    __shared__ __align__(16) u16 Bs[3][256 * 32];    // Gbt staging (gl_lds, 3-buf)
    __shared__ __align__(16) u16 ktc[2][32 * 68];    // kt chunk, dbuf, pitch 68
    __shared__ float rs[128];
    int t = threadIdx.x, lane = t & 63, w = t >> 6, quad = lane >> 4, l15 = lane & 15;
    int ti = w & 1;                              // score i-subtile (16 of 32)
    int wm = (w >> 1) * 64;                      // m-half (shared by score & agg)
    int wn = (w & 1) * 128;                      // agg n-half of 256

    if (t < 128) rs[t] = 0.f;

    // K-invariant q B-frags: B[k=h][col=m], 8 contiguous h per lane
    bf16x8 qf[4][2];
#pragma unroll
    for (int j = 0; j < 4; ++j)
#pragma unroll
        for (int kick = 0; kick < 2; ++kick)
            qf[j][kick] = *(const bf16x8*)&qb[(size_t)(m0 + wm + j*16 + l15) * 64 + kick*32 + quad*8];

    // prologue staging: Bs chunk 0, ktc chunk 0
    int br = t >> 2, bc = (t & 3) * 8;
#pragma unroll
    for (int g4 = 0; g4 < 4; ++g4)
        gl_lds16(Gbt + (size_t)(n0 + br + g4*64) * 1024 + bc, &Bs[0][(br + g4*64) * 32 + bc]);
    int ir = t >> 3, ch = (t & 7) * 8;
    {
        uint4 k0 = *(const uint4*)&kb[(size_t)ir * 64 + ch];
        *(uint4*)&ktc[0][ir * 68 + ch] = k0;
    }

    f32x4 acc[4][8] = {};
    float partial[4] = {0.f, 0.f, 0.f, 0.f};

    for (int kk = 0; kk <= 32; ++kk) {
        int sb = kk & 1;                           // score-side buffer (ktc, As)
        __syncthreads();                           // the ONLY barrier per iter
        if (kk < 31) {                             // issue next Gbt chunk; lands by barrier kk+1,
                                                   // consumed at iter kk+2 (full iter in flight)
            int dst = (kk + 1) % 3;
#pragma unroll
            for (int g4 = 0; g4 < 4; ++g4)
                gl_lds16(Gbt + (size_t)(n0 + br + g4*64) * 1024 + (kk+1)*32 + bc,
                         &Bs[dst][(br + g4*64) * 32 + bc]);
        }
        uint4 kregn;
        if (kk < 31)                               // next kt chunk (global/L2, coalesced-ish)
            kregn = *(const uint4*)&kb[(size_t)((kk + 1) * 32 + ir) * 64 + ch];
        if (kk < 32) {
            // ---- score step kk: S^T[i][m] for i-subtile ti, m in wave's 64-half
            f32x4 sacc[4] = {};
#pragma unroll
            for (int kick = 0; kick < 2; ++kick) {
                bf16x8 ktf = *(const bf16x8*)&ktc[sb][(ti*16 + l15) * 68 + kick*32 + quad*8];
#pragma unroll
                for (int j = 0; j < 4; ++j)
                    sacc[j] = __builtin_amdgcn_mfma_f32_16x16x32_bf16(ktf, qf[j][kick], sacc[j], 0, 0, 0);
            }
            // ---- epilogue: square, weighted rowsum partial, pack to As[sb]
            float4 g = *(const float4*)&Grsum[kk * 32 + ti * 16 + quad * 4];
#pragma unroll
            for (int j = 0; j < 4; ++j) {
                float v0 = sacc[j][0] * 0.125f + 1e-9f; v0 *= v0;
                float v1 = sacc[j][1] * 0.125f + 1e-9f; v1 *= v1;
                float v2 = sacc[j][2] * 0.125f + 1e-9f; v2 *= v2;
                float v3 = sacc[j][3] * 0.125f + 1e-9f; v3 *= v3;
                partial[j] += v0 * g.x + v1 * g.y + v2 * g.z + v3 * g.w;
                uint2 pk = { pack2(v0, v1), pack2(v2, v3) };
                *(uint2*)&As[sb][(wm + j*16 + l15) * 40 + ti*16 + quad*4] = pk;
            }
        }
        if (kk > 0) {
            // ---- agg step kk-1: wave's 64m x 128n from As[sb^1] @ Bs[(kk-1)%3]
            int bb = (kk - 1) % 3;
            int kh = quad * 8;
            bf16x8 af[4];
#pragma unroll
            for (int i = 0; i < 4; ++i)
                af[i] = *(const bf16x8*)&As[sb ^ 1][(wm + i*16 + l15) * 40 + kh];
#pragma unroll
            for (int jh = 0; jh < 2; ++jh) {
                bf16x8 bfr[4];
#pragma unroll
                for (int j = 0; j < 4; ++j)
                    bfr[j] = *(const bf16x8*)&Bs[bb][(wn + jh*64 + j*16 + l15) * 32 + kh];
#pragma unroll
                for (int i = 0; i < 4; ++i)
#pragma unroll
                    for (int j = 0; j < 4; ++j)
                        acc[i][jh*4 + j] = __builtin_amdgcn_mfma_f32_16x16x32_bf16(af[i], bfr[j], acc[i][jh*4 + j], 0, 0, 0);
            }
        }
        if (kk < 31)                               // stage next kt chunk (readers of ktc[sb^1]
            *(uint4*)&ktc[sb ^ 1][ir * 68 + ch] = kregn;   // were pre-barrier of THIS iter)
    }

    // rowsum: reduce quads (same m, different i-subsets), combine waves via LDS
#pragma unroll
    for (int j = 0; j < 4; ++j) {
        partial[j] += __shfl_xor(partial[j], 16, 64);
        partial[j] += __shfl_xor(partial[j], 32, 64);
    }
    if (quad == 0)
#pragma unroll
        for (int j = 0; j < 4; ++j) atomicAdd(&rs[wm + j*16 + l15], partial[j]);
    __syncthreads();
    if (t < 128) rs[t] = 1.0f / (rs[t] + 0.001f);
    __syncthreads();

#pragma unroll
    for (int i = 0; i < 4; ++i) {
        float4 rv = *(const float4*)&rs[wm + i * 16 + quad * 4];
        float rva[4] = { rv.x, rv.y, rv.z, rv.w };
#pragma unroll
        for (int r = 0; r < 4; ++r) {
            int m = m0 + wm + i * 16 + quad * 4 + r;
            float* orow = out + (size_t)m * (BATCH * IN_DIM) + (size_t)b * IN_DIM + n0 + wn;
#pragma unroll
            for (int j = 0; j < 8; ++j)
                orow[j * 16 + l15] = acc[i][j][r] * rva[r];
        }
    }
}

// ---------------------------------------------------------------------------
extern "C" void kernel_launch(void* const* d_in, const int* in_sizes, int n_in,
                              void* d_out, int out_size, void* d_ws, size_t ws_size,
                              hipStream_t stream) {
    const float* s  = (const float*)d_in[0];
    const float* G  = (const float*)d_in[1];
    const float* Q  = (const float*)d_in[2];
    const float* Kw = (const float*)d_in[3];
    float* out = (float*)d_out;
    char* ws = (char*)d_ws;

    u16*   qws   = (u16*)(ws);                                    // 2 MB
    u16*   ktws  = (u16*)(ws + (size_t)(2u << 20));               // 2 MB
    u16*   Gbt   = (u16*)(ws + (size_t)(4u << 20));               // 2 MB
    u16*   QT    = (u16*)(ws + (size_t)(6u << 20));               // 128 KB
    u16*   KwT   = (u16*)(ws + (size_t)(6u << 20) + (128u << 10)); // 128 KB
    float* Grsum = (float*)(ws + (size_t)(6u << 20) + (256u << 10)); // 4 KB
    float* Grp   = (float*)(ws + (size_t)(6u << 20) + (260u << 10)); // 64 KB

    prep<<<768, 256, 0, stream>>>(G, Q, Kw, Gbt, Grp, QT, KwT);
    qkt<<<dim3(16, 16, 2), 512, 0, stream>>>(s, QT, KwT, Grp, qws, ktws, Grsum);
    gemm_fused<<<dim3(4, 8, 16), 256, 0, stream>>>(qws, ktws, Gbt, Grsum, out);
}